// Round 1
// baseline (342.713 us; speedup 1.0000x reference)
//
#include <hip/hip_runtime.h>
#include <hip/hip_bf16.h>

#define MEM   2000
#define FEA   256
#define ROWS  32
#define LSTR  2056      // logits row stride (ushorts): 2048 pad + 8 -> 2-way banks, 16B aligned
#define XSTR  264       // xr row stride (ushorts)
#define OSTR  265       // out-stage row stride (floats), odd -> conflict-free column reads
#define KPAD  2048
#define OUTN  8388608   // 32*256*32*32

typedef float f32x4 __attribute__((ext_vector_type(4)));
typedef short s16x8 __attribute__((ext_vector_type(8)));

__device__ __forceinline__ unsigned short f2b(float f) {
    unsigned u = __builtin_bit_cast(unsigned, f);
    u = u + 0x7fffu + ((u >> 16) & 1u);   // RNE
    return (unsigned short)(u >> 16);
}
__device__ __forceinline__ float b2f(unsigned short h) {
    unsigned u = ((unsigned)h) << 16;
    return __builtin_bit_cast(float, u);
}

// ---------------- prep: W -> bf16 Wb, bf16 transposed WTb (K padded), sq, loss init ---------
__global__ __launch_bounds__(256) void prep_kernel(const float* __restrict__ W,
                                                   unsigned short* __restrict__ Wb,
                                                   unsigned short* __restrict__ WTb,
                                                   float* __restrict__ sq,
                                                   float* __restrict__ loss) {
    __shared__ float Wl[16][260];
    int t = threadIdx.x;
    int m0 = blockIdx.x << 4;
    int ml = t >> 4, cl = t & 15;
    for (int i = 0; i < 16; ++i) {
        int c = cl + (i << 4);
        float v = W[(m0 + ml) * FEA + c];
        Wl[ml][c] = v;
        Wb[(m0 + ml) * FEA + c] = f2b(v);
    }
    __syncthreads();
    // squared norms
    float s = 0.f;
    for (int i = 0; i < 16; ++i) { float v = Wl[ml][cl + (i << 4)]; s += v * v; }
    s += __shfl_xor(s, 1); s += __shfl_xor(s, 2); s += __shfl_xor(s, 4); s += __shfl_xor(s, 8);
    if (cl == 0) sq[m0 + ml] = s;
    // transpose write: WTb[c][m]
    int mm = t & 15, cg = t >> 4;
    for (int i = 0; i < 16; ++i) {
        int c = cg + (i << 4);
        WTb[c * KPAD + m0 + mm] = f2b(Wl[mm][c]);
    }
    if (blockIdx.x == 0) {
        for (int c = t; c < FEA; c += 256)
            for (int m = MEM; m < KPAD; ++m) WTb[c * KPAD + m] = 0;
        if (t == 0) {
            loss[0] = 0.0f;                                  // compact accumulates here
            loss[1] = -2000.0f / (2000.0f * 1999.0f);        // distance: -trace/(m(m-1))
        }
    }
}

// ---------------- main fused kernel: 32 rows/block, 8 waves -------------------------------
__global__ __launch_bounds__(512, 1) void main_kernel(const float* __restrict__ inp,
                                                      const float* __restrict__ posb,
                                                      const float* __restrict__ W,
                                                      const unsigned short* __restrict__ Wb,
                                                      const unsigned short* __restrict__ WTb,
                                                      float* __restrict__ out,
                                                      float* __restrict__ loss) {
    __shared__ __align__(16) unsigned short sL[ROWS * LSTR];   // logits -> a (bf16); reused as f32 out-stage
    __shared__ __align__(16) unsigned short sX[ROWS * XSTR];   // xr bf16
    __shared__ float sMax[ROWS];
    __shared__ int   sIdx[ROWS];
    __shared__ float sThr[ROWS];
    __shared__ float sInv[ROWS];
    __shared__ float sCl;

    int t = threadIdx.x;
    int blk = blockIdx.x;
    int b = blk >> 5, hw0 = (blk & 31) << 5;
    const float* ip = inp + (size_t)b * 262144 + hw0;
    const float* pp = posb + hw0;
    if (t == 0) sCl = 0.0f;

    // stage xr = input + pos (transposed to [hw][c]) as bf16
    {
        int hw = t & 31, c0 = t >> 5;
        for (int i = 0; i < 16; ++i) {
            int c = c0 + (i << 4);
            float v = ip[c * 1024 + hw] + pp[c * 1024 + hw];
            sX[hw * XSTR + c] = f2b(v);
        }
    }
    __syncthreads();

    int w = t >> 6, lane = t & 63;
    int ar = lane & 15, ag = lane >> 4;

    // A-fragments for all 32 rows (64 VGPR/lane)
    s16x8 af[2][8];
#pragma unroll
    for (int rt = 0; rt < 2; ++rt)
#pragma unroll
        for (int q = 0; q < 8; ++q)
            af[rt][q] = *(const s16x8*)&sX[(rt * 16 + ar) * XSTR + q * 32 + ag * 8];

    // ---- GEMM1: logits = xr @ W^T  (slot tiles round-robin over waves) ----
    for (int st = w; st < 125; st += 8) {
        int m0 = st << 4;
        const unsigned short* wp = Wb + (m0 + ar) * FEA + ag * 8;
        f32x4 a0 = {0.f, 0.f, 0.f, 0.f}, a1 = {0.f, 0.f, 0.f, 0.f};
#pragma unroll
        for (int q = 0; q < 8; ++q) {
            s16x8 bf = *(const s16x8*)(wp + q * 32);
            a0 = __builtin_amdgcn_mfma_f32_16x16x32_bf16(af[0][q], bf, a0, 0, 0, 0);
            a1 = __builtin_amdgcn_mfma_f32_16x16x32_bf16(af[1][q], bf, a1, 0, 0, 0);
        }
        int col = m0 + ar, r0 = ag << 2;
#pragma unroll
        for (int i = 0; i < 4; ++i) {
            sL[(r0 + i) * LSTR + col]        = f2b(a0[i]);
            sL[(16 + r0 + i) * LSTR + col]   = f2b(a1[i]);
        }
    }
    __syncthreads();

    // ---- stats: per-row max + argmax (16 threads/row) ----
    int row = t >> 4, s16 = t & 15;
    unsigned short* Lr = sL + row * LSTR;
    {
        float mx = -1e30f; int mi = 0;
        for (int j = s16; j < 250; j += 16) {
            s16x8 v = *(const s16x8*)(Lr + j * 8);
#pragma unroll
            for (int e = 0; e < 8; ++e) {
                float f = b2f((unsigned short)v[e]);
                if (f > mx) { mx = f; mi = j * 8 + e; }
            }
        }
#pragma unroll
        for (int d = 1; d < 16; d <<= 1) {
            float omx = __shfl_xor(mx, d); int omi = __shfl_xor(mi, d);
            if (omx > mx || (omx == mx && omi < mi)) { mx = omx; mi = omi; }
        }
        if (s16 == 0) { sMax[row] = mx; sIdx[row] = mi; }
    }
    __syncthreads();

    // ---- a = exp(l - max) written back as bf16; Z; pad-zero; thr = s*Z ----
    {
        float mx = sMax[row];
        float z = 0.f;
        for (int j = s16; j < 250; j += 16) {
            s16x8 v = *(const s16x8*)(Lr + j * 8);
#pragma unroll
            for (int e = 0; e < 8; ++e) {
                float f = b2f((unsigned short)v[e]);
                float a = exp2f((f - mx) * 1.4426950408889634f);
                z += a;
                v[e] = (short)f2b(a);
            }
            *(s16x8*)(Lr + j * 8) = v;
        }
        if (s16 < 6) {  // zero K-pad slots 2000..2047
            s16x8 zz = {0, 0, 0, 0, 0, 0, 0, 0};
            *(s16x8*)(Lr + 2000 + s16 * 8) = zz;
        }
        z += __shfl_xor(z, 1); z += __shfl_xor(z, 2); z += __shfl_xor(z, 4); z += __shfl_xor(z, 8);
        if (s16 == 0) sThr[row] = z * 0.0025f;
    }
    __syncthreads();

    // ---- shrink mask in-place + masked denom ----
    {
        float thr = sThr[row];
        float den = 0.f;
        for (int j = s16; j < 250; j += 16) {
            s16x8 v = *(const s16x8*)(Lr + j * 8);
#pragma unroll
            for (int e = 0; e < 8; ++e) {
                float f = b2f((unsigned short)v[e]);
                if (f > thr) den += f; else v[e] = 0;
            }
            *(s16x8*)(Lr + j * 8) = v;
        }
        den += __shfl_xor(den, 1); den += __shfl_xor(den, 2); den += __shfl_xor(den, 4); den += __shfl_xor(den, 8);
        if (s16 == 0) sInv[row] = den > 0.f ? 1.0f / den : 0.0f;
    }
    // ---- compact loss (uses sIdx, stable since stats barrier) ----
    {
        const float* wr = W + (size_t)sIdx[row] * FEA;
        float cl = 0.f;
        for (int i = 0; i < 16; ++i) {
            int c = s16 + (i << 4);
            float x = b2f(sX[row * XSTR + c]);
            float d = x - wr[c];
            cl += d * d;
        }
        cl += __shfl_xor(cl, 1); cl += __shfl_xor(cl, 2); cl += __shfl_xor(cl, 4); cl += __shfl_xor(cl, 8);
        if (s16 == 0) atomicAdd(&sCl, cl);
    }
    __syncthreads();

    // ---- GEMM2: out = a_masked @ W  (each wave owns 32 output channels) ----
    {
        int ct0 = w << 1;
        const unsigned short* wt0 = WTb + (ct0 * 16 + ar) * KPAD + ag * 8;
        const unsigned short* wt1 = wt0 + 16 * KPAD;
        const unsigned short* al0 = sL + ar * LSTR + ag * 8;
        const unsigned short* al1 = sL + (16 + ar) * LSTR + ag * 8;
        f32x4 c00 = {0.f,0.f,0.f,0.f}, c01 = {0.f,0.f,0.f,0.f};
        f32x4 c10 = {0.f,0.f,0.f,0.f}, c11 = {0.f,0.f,0.f,0.f};
        for (int k = 0; k < KPAD; k += 32) {
            s16x8 A0 = *(const s16x8*)(al0 + k);
            s16x8 A1 = *(const s16x8*)(al1 + k);
            s16x8 B0 = *(const s16x8*)(wt0 + k);
            s16x8 B1 = *(const s16x8*)(wt1 + k);
            c00 = __builtin_amdgcn_mfma_f32_16x16x32_bf16(A0, B0, c00, 0, 0, 0);
            c01 = __builtin_amdgcn_mfma_f32_16x16x32_bf16(A0, B1, c01, 0, 0, 0);
            c10 = __builtin_amdgcn_mfma_f32_16x16x32_bf16(A1, B0, c10, 0, 0, 0);
            c11 = __builtin_amdgcn_mfma_f32_16x16x32_bf16(A1, B1, c11, 0, 0, 0);
        }
        __syncthreads();           // everyone done reading sL -> reuse as f32 out-stage
        float* sO = (float*)sL;
        int r0 = ag << 2;
        int c0a = ct0 * 16 + ar, c1a = c0a + 16;
#pragma unroll
        for (int i = 0; i < 4; ++i) {
            sO[(r0 + i) * OSTR + c0a]      = c00[i] * sInv[r0 + i];
            sO[(r0 + i) * OSTR + c1a]      = c01[i] * sInv[r0 + i];
            sO[(16 + r0 + i) * OSTR + c0a] = c10[i] * sInv[16 + r0 + i];
            sO[(16 + r0 + i) * OSTR + c1a] = c11[i] * sInv[16 + r0 + i];
        }
    }
    __syncthreads();

    // ---- coalesced transposed store: out[b][c][hw] ----
    {
        const float* sO = (const float*)sL;
        int hw = t & 31, c0 = t >> 5;
        float* op = out + (size_t)b * 262144 + hw0 + hw;
        for (int i = 0; i < 16; ++i) {
            int c = c0 + (i << 4);
            op[c * 1024] = sO[hw * OSTR + c];
        }
    }
    if (t == 0) atomicAdd(loss, sCl * (1.0f / 8388608.0f));
}

// ---------------- distance loss: sum relu(1 - d2) over full matrix ------------------------
__global__ __launch_bounds__(256) void dist_kernel(const unsigned short* __restrict__ Wb,
                                                   const float* __restrict__ sq,
                                                   float* __restrict__ dl) {
    __shared__ float red[4];
    int t = threadIdx.x, w = t >> 6, lane = t & 63;
    int ar = lane & 15, ag = lane >> 4;
    int i0 = blockIdx.x << 4;
    s16x8 af[8];
#pragma unroll
    for (int q = 0; q < 8; ++q)
        af[q] = *(const s16x8*)(Wb + (i0 + ar) * FEA + q * 32 + ag * 8);
    float sqi[4];
#pragma unroll
    for (int e = 0; e < 4; ++e) sqi[e] = sq[i0 + (ag << 2) + e];
    float sum = 0.f;
    for (int jt = w; jt < 125; jt += 4) {
        int j0 = jt << 4;
        const unsigned short* wp = Wb + (j0 + ar) * FEA + ag * 8;
        f32x4 acc = {0.f, 0.f, 0.f, 0.f};
#pragma unroll
        for (int q = 0; q < 8; ++q) {
            s16x8 bf = *(const s16x8*)(wp + q * 32);
            acc = __builtin_amdgcn_mfma_f32_16x16x32_bf16(af[q], bf, acc, 0, 0, 0);
        }
        float sqj = sq[j0 + ar];
#pragma unroll
        for (int e = 0; e < 4; ++e) {
            float dist = 1.0f - (sqi[e] + sqj - 2.0f * acc[e]);
            sum += dist > 0.f ? dist : 0.f;
        }
    }
#pragma unroll
    for (int d = 1; d < 64; d <<= 1) sum += __shfl_xor(sum, d);
    if (lane == 0) red[w] = sum;
    __syncthreads();
    if (t == 0) {
        float s = red[0] + red[1] + red[2] + red[3];
        atomicAdd(dl, s * (1.0f / (2000.0f * 1999.0f)));
    }
}

extern "C" void kernel_launch(void* const* d_in, const int* in_sizes, int n_in,
                              void* d_out, int out_size, void* d_ws, size_t ws_size,
                              hipStream_t stream) {
    (void)in_sizes; (void)n_in; (void)out_size; (void)ws_size;
    const float* inp  = (const float*)d_in[0];
    const float* W    = (const float*)d_in[2];
    const float* posb = (const float*)d_in[3];
    float* out = (float*)d_out;

    unsigned short* Wb  = (unsigned short*)d_ws;             // 2000*256*2   = 1,024,000 B
    unsigned short* WTb = Wb + MEM * FEA;                    // 256*2048*2   = 1,048,576 B
    float* sq = (float*)(WTb + FEA * KPAD);                  // 2000*4       =     8,000 B

    hipLaunchKernelGGL(prep_kernel, dim3(125), dim3(256), 0, stream, W, Wb, WTb, sq, out + OUTN);
    hipLaunchKernelGGL(main_kernel, dim3(1024), dim3(512), 0, stream, inp, posb, W, Wb, WTb, out, out + OUTN);
    hipLaunchKernelGGL(dist_kernel, dim3(125), dim3(256), 0, stream, Wb, sq, out + OUTN + 1);
}

// Round 2
// 280.992 us; speedup vs baseline: 1.2197x; 1.2197x over previous
//
#include <hip/hip_runtime.h>
#include <hip/hip_bf16.h>

typedef unsigned char u8;
typedef unsigned short u16;
typedef unsigned int u32;
typedef float f32x4 __attribute__((ext_vector_type(4)));
typedef short s16x8 __attribute__((ext_vector_type(8)));

#define MEM    2000
#define FEA    256
#define SLSTR  2056      // fp8 a row stride (bytes)
#define XSTR   264       // xr row stride (u16)
#define OSTR   265       // out-stage row stride (f32)
#define G2BASE 65792     // = 32*SLSTR
#define SXBASE 131072    // = 4*32768 (G1 ring)
#define POOLSZ 147968    // SXBASE + 32*XSTR*2
#define OUTN   8388608   // 32*256*32*32

typedef const __attribute__((address_space(1))) u32* gp1;
typedef __attribute__((address_space(3))) u32* lp3;

__device__ __forceinline__ void gl_lds16(const void* g, void* l) {
    __builtin_amdgcn_global_load_lds((gp1)g, (lp3)l, 16, 0, 0);
}
__device__ __forceinline__ void pipe_bar() {
    __builtin_amdgcn_sched_barrier(0);
    __builtin_amdgcn_s_barrier();
    __builtin_amdgcn_sched_barrier(0);
}
__device__ __forceinline__ void lds_bar() {
    asm volatile("s_waitcnt lgkmcnt(0)" ::: "memory");
    pipe_bar();
}

__device__ __forceinline__ u16 f2b(float f) {
    u32 u = __builtin_bit_cast(u32, f);
    u = u + 0x7fffu + ((u >> 16) & 1u);
    return (u16)(u >> 16);
}
__device__ __forceinline__ float b2f(u16 h) {
    u32 u = ((u32)h) << 16;
    return __builtin_bit_cast(float, u);
}
// exact f32 -> e4m3fn (RNE), used in prep (handles subnormals)
__device__ __forceinline__ u8 f2e4m3(float x) {
    float ax = fabsf(x);
    u32 s = (__builtin_bit_cast(u32, x) >> 24) & 0x80u;
    if (ax >= 448.f) return (u8)(s | 0x7e);
    if (ax < 0.015625f) {
        int q = (int)rintf(ax * 512.f);
        return (u8)(s | (u32)q);
    }
    int e = (int)(__builtin_bit_cast(u32, ax) >> 23) - 127;
    float scale = __builtin_bit_cast(float, (u32)((127 - e + 3) << 23)); // 2^(3-e)
    int q = (int)rintf(ax * scale);   // [8,16]
    int E = e + 7;
    if (q == 16) { q = 8; E += 1; if (E > 15) return (u8)(s | 0x7e); }
    return (u8)(s | (u32)(E << 3) | (u32)(q & 7));
}
// fast f32 -> e4m3fn for v in {0} U [0.15, 64] (no subnormals needed)
__device__ __forceinline__ u32 f2e4m3_fast(float v) {
    u32 u = __builtin_bit_cast(u32, v);
    u += 0x0007FFFFu + ((u >> 20) & 1u);
    int bb = (int)(u >> 20) - 0x3C0;
    return bb < 0 ? 0u : (u32)bb;
}

// ---------------- prep: Wbs (bf16, swizzled, padded to 2048), WTc (fp8 x16, chunked+swizzled), sq
__global__ __launch_bounds__(256) void prep_kernel(const float* __restrict__ W,
                                                   u16* __restrict__ Wbs,
                                                   u8* __restrict__ WTc,
                                                   float* __restrict__ sqv,
                                                   float* __restrict__ loss) {
    int c = blockIdx.x, t = threadIdx.x;
    // Wbs + sq: thread -> slot (t>>2), channel quarter (t&3)*64
    int sl = t >> 2, ch0 = (t & 3) << 6;
    int slot = c * 64 + sl;
    float ss = 0.f;
    if (slot < MEM) {
        for (int i = 0; i < 64; ++i) {
            int ch = ch0 + i;
            float v = W[slot * 256 + ch];
            ss += v * v;
            Wbs[slot * 256 + (ch ^ ((slot & 7) << 3))] = f2b(v);
        }
    } else {
        for (int i = 0; i < 64; ++i) Wbs[slot * 256 + ch0 + i] = 0;
    }
    ss += __shfl_xor(ss, 1);
    ss += __shfl_xor(ss, 2);
    if ((t & 3) == 0 && slot < MEM) sqv[slot] = ss;
    // WTc: thread = channel, all 64 k of this chunk; value = W[k][ch]*16 in fp8
    int ch = t;
    for (int kl = 0; kl < 64; ++kl) {
        int s2 = c * 64 + kl;
        float v = (s2 < MEM) ? W[s2 * 256 + ch] * 16.f : 0.f;
        WTc[c * 16384 + ch * 64 + (kl ^ ((ch & 7) << 3))] = f2e4m3(v);
    }
    if (c == 0 && t == 0) {
        loss[0] = 0.0f;
        loss[1] = -2000.0f / (2000.0f * 1999.0f);
    }
}

// ---------------- main fused kernel ----------------
__global__ __launch_bounds__(512, 2) void main_kernel(
        const float* __restrict__ inp, const float* __restrict__ posb,
        const u16* __restrict__ Wbs, const u8* __restrict__ WTc,
        const float* __restrict__ sqv, float* __restrict__ out,
        float* __restrict__ loss) {
    __shared__ __align__(16) u8 pool[POOLSZ];
    __shared__ float sPM[4][32];
    __shared__ int   sPI[4][32];
    __shared__ float sPZ[4][32];
    __shared__ float sPD[4][32];
    __shared__ float sSSp[8][32];
    __shared__ float sMax[32];
    __shared__ float sThr[32];
    __shared__ float sInv[32];

    const int t = threadIdx.x;
    const int w = t >> 6, lane = t & 63;
    const int ar = lane & 15, ag = lane >> 4;
    const int blk = blockIdx.x, b = blk >> 5, hw0 = (blk & 31) << 5;
    const u8* WbsB = (const u8*)Wbs;

    // ---- G1 prologue: DMA chunks 0..2 into ring ----
#pragma unroll
    for (int c = 0; c < 3; ++c) {
        const u8* src = WbsB + c * 32768 + w * 4096 + lane * 16;
        u8* dst = pool + ((c & 3) << 15) + w * 4096;
#pragma unroll
        for (int i = 0; i < 4; ++i) gl_lds16(src + i * 1024, dst + i * 1024);
    }

    // ---- phase A: stage xr bf16 + per-row sum(x^2) ----
    {
        const int hw = t & 31, cq = t >> 5;
        const float* ip = inp + (size_t)b * 262144 + hw0 + hw;
        const float* pp = posb + hw0 + hw;
        u16* sX = (u16*)(pool + SXBASE);
        float ss = 0.f;
#pragma unroll
        for (int i = 0; i < 16; ++i) {
            int ch = cq + (i << 4);
            float v = ip[ch * 1024] + pp[ch * 1024];
            ss += v * v;
            sX[hw * XSTR + ch] = f2b(v);
        }
        ss += __shfl_xor(ss, 32);
        if (lane < 32) sSSp[w][lane] = ss;
    }
    lds_bar();

    const int rt = w >> 2, sq4 = w & 3;     // row-tile, slot-quarter
    const int slot_l = sq4 * 16 + ar;       // slot within 64-chunk

    s16x8 af[8];
    {
        const u16* sX = (const u16*)(pool + SXBASE);
#pragma unroll
        for (int q = 0; q < 8; ++q)
            af[q] = *(const s16x8*)(sX + (rt * 16 + ar) * XSTR + q * 32 + ag * 8);
    }

    // ---- GEMM1: logits in registers; W streamed via LDS ring ----
    f32x4 acc[32];
    {
        const int rowoff = slot_l * 512;
        const int swz = (slot_l & 7) << 4;
#pragma unroll
        for (int c = 0; c < 32; ++c) {
            if (c <= 29)      asm volatile("s_waitcnt vmcnt(8)" ::: "memory");
            else if (c == 30) asm volatile("s_waitcnt vmcnt(4)" ::: "memory");
            else              asm volatile("s_waitcnt vmcnt(0)" ::: "memory");
            pipe_bar();
            if (c <= 28) {
                const int cn = c + 3;
                const u8* src = WbsB + cn * 32768 + w * 4096 + lane * 16;
                u8* dst = pool + ((cn & 3) << 15) + w * 4096;
#pragma unroll
                for (int i = 0; i < 4; ++i) gl_lds16(src + i * 1024, dst + i * 1024);
            }
            const u8* base = pool + ((c & 3) << 15);
            f32x4 a = {0.f, 0.f, 0.f, 0.f};
#pragma unroll
            for (int kk = 0; kk < 8; ++kk) {
                s16x8 bf = *(const s16x8*)(base + ((rowoff + kk * 64 + ag * 16) ^ swz));
                a = __builtin_amdgcn_mfma_f32_16x16x32_bf16(af[kk], bf, a, 0, 0, 0);
            }
            acc[c] = a;
        }
    }

    // mask pad slots (chunk 31 slots >= 2000 belong to sq4>=1)
    if (sq4 != 0) {
        acc[31][0] = -3e38f; acc[31][1] = -3e38f; acc[31][2] = -3e38f; acc[31][3] = -3e38f;
    }

    // ---- in-register row max + argmax ----
    float bm[4]; int bi[4];
#pragma unroll
    for (int e = 0; e < 4; ++e) { bm[e] = acc[0][e]; bi[e] = 0; }
#pragma unroll
    for (int c = 1; c < 32; ++c)
#pragma unroll
        for (int e = 0; e < 4; ++e)
            if (acc[c][e] > bm[e]) { bm[e] = acc[c][e]; bi[e] = c; }
#pragma unroll
    for (int e = 0; e < 4; ++e) bi[e] = bi[e] * 64 + slot_l;
#pragma unroll
    for (int d = 1; d < 16; d <<= 1)
#pragma unroll
        for (int e = 0; e < 4; ++e) {
            float om = __shfl_xor(bm[e], d);
            int   oi = __shfl_xor(bi[e], d);
            if (om > bm[e] || (om == bm[e] && oi < bi[e])) { bm[e] = om; bi[e] = oi; }
        }
    if (ar == 0) {
#pragma unroll
        for (int e = 0; e < 4; ++e) {
            int row = rt * 16 + ag * 4 + e;
            sPM[sq4][row] = bm[e];
            sPI[sq4][row] = bi[e];
        }
    }
    lds_bar();

    // ---- G2 prologue (G1 ring region is dead now) ----
#pragma unroll
    for (int c = 0; c < 3; ++c) {
        const u8* src = WTc + c * 16384 + w * 2048 + lane * 16;
        u8* dst = pool + G2BASE + ((c & 3) << 14) + w * 2048;
#pragma unroll
        for (int i = 0; i < 2; ++i) gl_lds16(src + i * 1024, dst + i * 1024);
    }

    // ---- combine max/argmax + compact loss ----
    if (t < 32) {
        float mx = sPM[0][t]; int bid = sPI[0][t];
#pragma unroll
        for (int q = 1; q < 4; ++q) {
            float m2 = sPM[q][t]; int i2 = sPI[q][t];
            if (m2 > mx || (m2 == mx && i2 < bid)) { mx = m2; bid = i2; }
        }
        sMax[t] = mx;
        float ss = 0.f;
#pragma unroll
        for (int q = 0; q < 8; ++q) ss += sSSp[q][t];
        float term = ss - 2.f * mx + sqv[bid];
#pragma unroll
        for (int d = 1; d < 32; d <<= 1) term += __shfl_xor(term, d);
        if (t == 0) atomicAdd(loss, term * (1.0f / 8388608.0f));
    }
    lds_bar();

    // ---- exp (in-place) + Z ----
    float mxr[4], zz[4] = {0.f, 0.f, 0.f, 0.f};
#pragma unroll
    for (int e = 0; e < 4; ++e) mxr[e] = sMax[rt * 16 + ag * 4 + e];
#pragma unroll
    for (int c = 0; c < 32; ++c)
#pragma unroll
        for (int e = 0; e < 4; ++e) {
            float a = __expf(acc[c][e] - mxr[e]);
            acc[c][e] = a;
            zz[e] += a;
        }
#pragma unroll
    for (int d = 1; d < 16; d <<= 1)
#pragma unroll
        for (int e = 0; e < 4; ++e) zz[e] += __shfl_xor(zz[e], d);
    if (ar == 0)
#pragma unroll
        for (int e = 0; e < 4; ++e) sPZ[sq4][rt * 16 + ag * 4 + e] = zz[e];
    lds_bar();
    if (t < 32) sThr[t] = 0.0025f * (sPZ[0][t] + sPZ[1][t] + sPZ[2][t] + sPZ[3][t]);
    lds_bar();

    // ---- shrink mask + denom + write a as fp8 (x64) ----
    float thr[4], dd[4] = {0.f, 0.f, 0.f, 0.f};
#pragma unroll
    for (int e = 0; e < 4; ++e) thr[e] = sThr[rt * 16 + ag * 4 + e];
#pragma unroll
    for (int c = 0; c < 32; ++c) {
        int slot = c * 64 + slot_l;
#pragma unroll
        for (int e = 0; e < 4; ++e) {
            float a = acc[c][e];
            float v = 0.f;
            if (a > thr[e]) { dd[e] += a; v = a * 64.f; }
            pool[(rt * 16 + ag * 4 + e) * SLSTR + slot] = (u8)f2e4m3_fast(v);
        }
    }
#pragma unroll
    for (int d = 1; d < 16; d <<= 1)
#pragma unroll
        for (int e = 0; e < 4; ++e) dd[e] += __shfl_xor(dd[e], d);
    if (ar == 0)
#pragma unroll
        for (int e = 0; e < 4; ++e) sPD[sq4][rt * 16 + ag * 4 + e] = dd[e];
    lds_bar();
    if (t < 32) {
        float den = sPD[0][t] + sPD[1][t] + sPD[2][t] + sPD[3][t];
        sInv[t] = den > 0.f ? 1.0f / (1024.0f * den) : 0.0f;
    }
    lds_bar();

    // ---- GEMM2: out = a_fp8 @ WT_fp8, WT streamed via LDS ring ----
    f32x4 oa00 = {0.f,0.f,0.f,0.f}, oa01 = {0.f,0.f,0.f,0.f};
    f32x4 oa10 = {0.f,0.f,0.f,0.f}, oa11 = {0.f,0.f,0.f,0.f};
    const int ch0 = (w * 2) * 16 + ar;
    const int ch1 = (w * 2 + 1) * 16 + ar;
    int bo[2][2];
#pragma unroll
    for (int kk = 0; kk < 2; ++kk) {
        bo[0][kk] = (ch0 * 64 + kk * 32 + ag * 8) ^ ((ch0 & 7) << 3);
        bo[1][kk] = (ch1 * 64 + kk * 32 + ag * 8) ^ ((ch1 & 7) << 3);
    }
    const u8* sLr0 = pool + ar * SLSTR + ag * 8;
    const u8* sLr1 = pool + (16 + ar) * SLSTR + ag * 8;
#pragma unroll
    for (int c = 0; c < 32; ++c) {
        if (c <= 29)      asm volatile("s_waitcnt vmcnt(4)" ::: "memory");
        else if (c == 30) asm volatile("s_waitcnt vmcnt(2)" ::: "memory");
        else              asm volatile("s_waitcnt vmcnt(0)" ::: "memory");
        pipe_bar();
        if (c <= 28) {
            const int cn = c + 3;
            const u8* src = WTc + cn * 16384 + w * 2048 + lane * 16;
            u8* dst = pool + G2BASE + ((cn & 3) << 14) + w * 2048;
#pragma unroll
            for (int i = 0; i < 2; ++i) gl_lds16(src + i * 1024, dst + i * 1024);
        }
        const u8* base = pool + G2BASE + ((c & 3) << 14);
        long long A00 = *(const long long*)(sLr0 + c * 64);
        long long A01 = *(const long long*)(sLr0 + c * 64 + 32);
        long long A10 = *(const long long*)(sLr1 + c * 64);
        long long A11 = *(const long long*)(sLr1 + c * 64 + 32);
        long long B00 = *(const long long*)(base + bo[0][0]);
        long long B01 = *(const long long*)(base + bo[0][1]);
        long long B10 = *(const long long*)(base + bo[1][0]);
        long long B11 = *(const long long*)(base + bo[1][1]);
        oa00 = __builtin_amdgcn_mfma_f32_16x16x32_fp8_fp8(A00, B00, oa00, 0, 0, 0);
        oa00 = __builtin_amdgcn_mfma_f32_16x16x32_fp8_fp8(A01, B01, oa00, 0, 0, 0);
        oa01 = __builtin_amdgcn_mfma_f32_16x16x32_fp8_fp8(A10, B00, oa01, 0, 0, 0);
        oa01 = __builtin_amdgcn_mfma_f32_16x16x32_fp8_fp8(A11, B01, oa01, 0, 0, 0);
        oa10 = __builtin_amdgcn_mfma_f32_16x16x32_fp8_fp8(A00, B10, oa10, 0, 0, 0);
        oa10 = __builtin_amdgcn_mfma_f32_16x16x32_fp8_fp8(A01, B11, oa10, 0, 0, 0);
        oa11 = __builtin_amdgcn_mfma_f32_16x16x32_fp8_fp8(A10, B10, oa11, 0, 0, 0);
        oa11 = __builtin_amdgcn_mfma_f32_16x16x32_fp8_fp8(A11, B11, oa11, 0, 0, 0);
    }
    lds_bar();   // all sL reads done; reuse pool[0..) as f32 out-stage

    {
        float* sO = (float*)pool;
#pragma unroll
        for (int i = 0; i < 4; ++i) {
            int r0 = ag * 4 + i, r1 = 16 + ag * 4 + i;
            sO[r0 * OSTR + ch0] = oa00[i] * sInv[r0];
            sO[r1 * OSTR + ch0] = oa01[i] * sInv[r1];
            sO[r0 * OSTR + ch1] = oa10[i] * sInv[r0];
            sO[r1 * OSTR + ch1] = oa11[i] * sInv[r1];
        }
    }
    lds_bar();
    {
        const float* sO = (const float*)pool;
        const int hw = t & 31, cq = t >> 5;
        float* op = out + (size_t)b * 262144 + hw0 + hw;
#pragma unroll
        for (int i = 0; i < 16; ++i) {
            int ch = cq + (i << 4);
            op[ch * 1024] = sO[hw * OSTR + ch];
        }
    }
}

// ---------------- distance loss (bf16 W@W^T from swizzled Wbs) ----------------
__global__ __launch_bounds__(256) void dist_kernel(const u16* __restrict__ Wbs,
                                                   const float* __restrict__ sqv,
                                                   float* __restrict__ dl) {
    __shared__ float red[4];
    int t = threadIdx.x, w = t >> 6, lane = t & 63;
    int ar = lane & 15, ag = lane >> 4;
    int i0 = blockIdx.x << 4;
    int si = i0 + ar;
    s16x8 af[8];
#pragma unroll
    for (int q = 0; q < 8; ++q)
        af[q] = *(const s16x8*)&Wbs[si * 256 + ((q * 32 + ag * 8) ^ ((si & 7) << 3))];
    float sqi[4];
#pragma unroll
    for (int e = 0; e < 4; ++e) sqi[e] = sqv[i0 + (ag << 2) + e];
    float sum = 0.f;
    for (int jt = w; jt < 125; jt += 4) {
        int j0 = jt << 4, sj0 = j0 + ar;
        f32x4 acc = {0.f, 0.f, 0.f, 0.f};
#pragma unroll
        for (int q = 0; q < 8; ++q) {
            s16x8 bf = *(const s16x8*)&Wbs[sj0 * 256 + ((q * 32 + ag * 8) ^ ((sj0 & 7) << 3))];
            acc = __builtin_amdgcn_mfma_f32_16x16x32_bf16(af[q], bf, acc, 0, 0, 0);
        }
        float sqj = sqv[sj0];
#pragma unroll
        for (int e = 0; e < 4; ++e) {
            float dist = 1.0f - (sqi[e] + sqj - 2.0f * acc[e]);
            sum += dist > 0.f ? dist : 0.f;
        }
    }
#pragma unroll
    for (int d = 1; d < 64; d <<= 1) sum += __shfl_xor(sum, d);
    if (lane == 0) red[w] = sum;
    __syncthreads();
    if (t == 0) {
        float s = red[0] + red[1] + red[2] + red[3];
        atomicAdd(dl, s * (1.0f / (2000.0f * 1999.0f)));
    }
}

extern "C" void kernel_launch(void* const* d_in, const int* in_sizes, int n_in,
                              void* d_out, int out_size, void* d_ws, size_t ws_size,
                              hipStream_t stream) {
    (void)in_sizes; (void)n_in; (void)out_size; (void)ws_size;
    const float* inp  = (const float*)d_in[0];
    const float* W    = (const float*)d_in[2];
    const float* posb = (const float*)d_in[3];
    float* out = (float*)d_out;

    u16* Wbs = (u16*)d_ws;                                   // 2048*256*2 = 1,048,576 B
    u8*  WTc = (u8*)d_ws + 1048576;                          // 32*16384   =   524,288 B
    float* sqv = (float*)((u8*)d_ws + 1048576 + 524288);     // 2000*4     =     8,000 B

    hipLaunchKernelGGL(prep_kernel, dim3(32), dim3(256), 0, stream, W, Wbs, WTc, sqv, out + OUTN);
    hipLaunchKernelGGL(main_kernel, dim3(1024), dim3(512), 0, stream, inp, posb, Wbs, WTc, sqv, out, out + OUTN);
    hipLaunchKernelGGL(dist_kernel, dim3(125), dim3(256), 0, stream, Wbs, sqv, out + OUTN + 1);
}

// Round 3
// 213.690 us; speedup vs baseline: 1.6038x; 1.3150x over previous
//
#include <hip/hip_runtime.h>
#include <hip/hip_bf16.h>

typedef unsigned char u8;
typedef unsigned short u16;
typedef unsigned int u32;
typedef unsigned long long u64;
typedef float f32x4 __attribute__((ext_vector_type(4)));
typedef short s16x8 __attribute__((ext_vector_type(8)));

#define MEM    2000
#define FEA    256
#define SLSTR  2056      // fp8 a row stride (bytes), 4B aligned
#define XSTR   264       // xr row stride (u16)
#define OSTR   265       // out-stage row stride (f32)
#define G2BASE 65792     // = 32*SLSTR
#define SXBASE 131072    // = 4*32768 (G1 ring)
#define POOLSZ 147968    // SXBASE + 32*XSTR*2
#define OUTN   8388608   // 32*256*32*32

typedef const __attribute__((address_space(1))) u32* gp1;
typedef __attribute__((address_space(3))) u32* lp3;

__device__ __forceinline__ void gl_lds16(const void* g, void* l) {
    __builtin_amdgcn_global_load_lds((gp1)g, (lp3)l, 16, 0, 0);
}
__device__ __forceinline__ void pipe_bar() {
    __builtin_amdgcn_sched_barrier(0);
    __builtin_amdgcn_s_barrier();
    __builtin_amdgcn_sched_barrier(0);
}
__device__ __forceinline__ void lds_bar() {
    asm volatile("s_waitcnt lgkmcnt(0)" ::: "memory");
    pipe_bar();
}

__device__ __forceinline__ u16 f2b(float f) {
    u32 u = __builtin_bit_cast(u32, f);
    u = u + 0x7fffu + ((u >> 16) & 1u);
    return (u16)(u >> 16);
}
// exact f32 -> e4m3fn (RNE) incl. subnormals (prep only)
__device__ __forceinline__ u8 f2e4m3(float x) {
    float ax = fabsf(x);
    u32 s = (__builtin_bit_cast(u32, x) >> 24) & 0x80u;
    if (ax >= 448.f) return (u8)(s | 0x7e);
    if (ax < 0.015625f) {
        int q = (int)rintf(ax * 512.f);
        return (u8)(s | (u32)q);
    }
    int e = (int)(__builtin_bit_cast(u32, ax) >> 23) - 127;
    float scale = __builtin_bit_cast(float, (u32)((127 - e + 3) << 23)); // 2^(3-e)
    int q = (int)rintf(ax * scale);   // [8,16]
    int E = e + 7;
    if (q == 16) { q = 8; E += 1; if (E > 15) return (u8)(s | 0x7e); }
    return (u8)(s | (u32)(E << 3) | (u32)(q & 7));
}
// fast f32 -> e4m3fn for v in {0} U [0.15, 64]
__device__ __forceinline__ u32 f2e4m3_fast(float v) {
    u32 u = __builtin_bit_cast(u32, v);
    u += 0x0007FFFFu + ((u >> 20) & 1u);
    int bb = (int)(u >> 20) - 0x3C0;
    return bb < 0 ? 0u : (u32)bb;
}

// ---------------- prep: Wbs (bf16 swizzled), WTc (fp8 x16 chunked+swizzled), sqv ------------
__global__ __launch_bounds__(256) void prep_kernel(const float* __restrict__ W,
                                                   u16* __restrict__ Wbs,
                                                   u8* __restrict__ WTc,
                                                   float* __restrict__ sqv,
                                                   float* __restrict__ loss) {
    const int blk = blockIdx.x, t = threadIdx.x;
    const int m0 = blk * 8;
    // --- Wbs + sqv: thread (sl = t>>5, cl = t&31), 8 contiguous channels each ---
    {
        const int sl = t >> 5, cl = t & 31;
        const int slot = m0 + sl;
        const int ch0 = cl * 8;
        const float* wr = W + slot * 256 + ch0;
        f32x4 v0 = *(const f32x4*)wr;
        f32x4 v1 = *(const f32x4*)(wr + 4);
        float ss = v0[0]*v0[0] + v0[1]*v0[1] + v0[2]*v0[2] + v0[3]*v0[3]
                 + v1[0]*v1[0] + v1[1]*v1[1] + v1[2]*v1[2] + v1[3]*v1[3];
        ss += __shfl_xor(ss, 1); ss += __shfl_xor(ss, 2); ss += __shfl_xor(ss, 4);
        ss += __shfl_xor(ss, 8); ss += __shfl_xor(ss, 16);
        if (cl == 0) sqv[slot] = ss;
        s16x8 pk;
#pragma unroll
        for (int i = 0; i < 4; ++i) { pk[i] = (short)f2b(v0[i]); pk[4 + i] = (short)f2b(v1[i]); }
        *(s16x8*)&Wbs[slot * 256 + (ch0 ^ ((slot & 7) << 3))] = pk;
    }
    // --- WTc: thread = channel; 8 slots of this block; fp8(w*16) packed 8B ---
    {
        const int ch = t;
        const int chunk = m0 >> 6, kl0 = m0 & 63;
        u32 lo = 0, hi = 0;
#pragma unroll
        for (int i = 0; i < 8; ++i) {
            u32 bb = f2e4m3(W[(m0 + i) * 256 + ch] * 16.f);
            if (i < 4) lo |= bb << (i * 8); else hi |= bb << ((i - 4) * 8);
        }
        u8* dst = WTc + chunk * 16384 + ch * 64 + (kl0 ^ ((ch & 7) << 3));
        *(u32*)dst = lo;
        *(u32*)(dst + 4) = hi;
    }
    if (blk == 0 && t == 0) {
        loss[0] = 0.0f;
        loss[1] = -2000.0f / (2000.0f * 1999.0f);
    }
}

// ---------------- main fused kernel ----------------
__global__ __launch_bounds__(512, 2) void main_kernel(
        const float* __restrict__ inp, const float* __restrict__ posb,
        const u16* __restrict__ Wbs, const u8* __restrict__ WTc,
        const float* __restrict__ sqv, float* __restrict__ out,
        float* __restrict__ loss) {
    __shared__ __align__(16) u8 pool[POOLSZ];
    __shared__ float sPM[4][32];
    __shared__ int   sPI[4][32];
    __shared__ float sPZ[4][32];
    __shared__ float sPD[4][32];
    __shared__ float sSSp[8][32];
    __shared__ float sMax[32];
    __shared__ float sThr[32];
    __shared__ float sInv[32];

    const int t = threadIdx.x;
    const int w = t >> 6, lane = t & 63;
    const int ar = lane & 15, ag = lane >> 4;
    const int blk = blockIdx.x, b = blk >> 5, hw0 = (blk & 31) << 5;
    const int rot = (blk >> 3) & 31;           // de-contention: co-resident XCD blocks read different chunks
    const u8* WbsB = (const u8*)Wbs;

    // ---- G1 prologue: DMA logical chunks 0..2 (physical rot..rot+2) ----
#pragma unroll
    for (int c = 0; c < 3; ++c) {
        const int cc = (c + rot) & 31;
        const u8* src = WbsB + cc * 32768 + w * 4096 + lane * 16;
        u8* dst = pool + ((c & 3) << 15) + w * 4096;
#pragma unroll
        for (int i = 0; i < 4; ++i) gl_lds16(src + i * 1024, dst + i * 1024);
    }

    // ---- stage xr bf16 + per-row sum(x^2) ----
    {
        const int hw = t & 31, cq = t >> 5;
        const float* ip = inp + (size_t)b * 262144 + hw0 + hw;
        const float* pp = posb + hw0 + hw;
        u16* sX = (u16*)(pool + SXBASE);
        float ss = 0.f;
#pragma unroll
        for (int i = 0; i < 16; ++i) {
            int ch = cq + (i << 4);
            float v = ip[ch * 1024] + pp[ch * 1024];
            ss += v * v;
            sX[hw * XSTR + ch] = f2b(v);
        }
        ss += __shfl_xor(ss, 32);
        if (lane < 32) sSSp[w][lane] = ss;
    }
    lds_bar();

    const int rt = w >> 2, sq4 = w & 3;        // row-tile, slot-quarter
    const int slot_l = sq4 * 16 + ar;          // W-row within 64-chunk (A-frag row)
    const int sb = sq4 * 16 + ag * 4;          // slot base of this thread's C-outputs
    const int row_a = rt * 16 + ar;            // this thread's xr row (all its logits)

    s16x8 af[8];
    {
        const u16* sX = (const u16*)(pool + SXBASE);
#pragma unroll
        for (int q = 0; q < 8; ++q)
            af[q] = *(const s16x8*)(sX + (rt * 16 + ar) * XSTR + q * 32 + ag * 8);
    }

    // ---- GEMM1 (swapped): acc[c][e] = logit[row_a][slot = phys(c)*64 + sb + e] ----
    f32x4 acc[32];
    {
        const int rowoff = slot_l * 512;
        const int swz = (slot_l & 7) << 4;
        const int c31 = (31 - rot) & 31;       // logical index of physical chunk 31 (pad slots)
#pragma unroll
        for (int c = 0; c < 32; ++c) {
            if (c <= 29)      asm volatile("s_waitcnt vmcnt(8)" ::: "memory");
            else if (c == 30) asm volatile("s_waitcnt vmcnt(4)" ::: "memory");
            else              asm volatile("s_waitcnt vmcnt(0)" ::: "memory");
            pipe_bar();
            if (c <= 28) {
                const int cn = (c + 3 + rot) & 31;
                const u8* src = WbsB + cn * 32768 + w * 4096 + lane * 16;
                u8* dst = pool + (((c + 3) & 3) << 15) + w * 4096;
#pragma unroll
                for (int i = 0; i < 4; ++i) gl_lds16(src + i * 1024, dst + i * 1024);
            }
            const u8* base = pool + ((c & 3) << 15);
            f32x4 a = {0.f, 0.f, 0.f, 0.f};
#pragma unroll
            for (int kk = 0; kk < 8; ++kk) {
                s16x8 bf = *(const s16x8*)(base + ((rowoff + kk * 64 + ag * 16) ^ swz));
                a = __builtin_amdgcn_mfma_f32_16x16x32_bf16(bf, af[kk], a, 0, 0, 0);
            }
            if (c == c31 && sq4 != 0) { a[0] = -3e38f; a[1] = -3e38f; a[2] = -3e38f; a[3] = -3e38f; }
            acc[c] = a;
        }
    }

    // ---- per-thread max + argmax (one row per thread) ----
    {
        float bm = -3e38f; int bi = 0x7fffffff;
#pragma unroll
        for (int c = 0; c < 32; ++c) {
            const int cb = (((c + rot) & 31) << 6) + sb;
#pragma unroll
            for (int e = 0; e < 4; ++e) {
                float f = acc[c][e];
                int id = cb + e;
                if (f > bm || (f == bm && id < bi)) { bm = f; bi = id; }
            }
        }
#pragma unroll
        for (int d = 16; d < 64; d <<= 1) {
            float om = __shfl_xor(bm, d);
            int   oi = __shfl_xor(bi, d);
            if (om > bm || (om == bm && oi < bi)) { bm = om; bi = oi; }
        }
        if (lane < 16) { sPM[sq4][rt * 16 + lane] = bm; sPI[sq4][rt * 16 + lane] = bi; }
    }
    lds_bar();

    // ---- G2 prologue (G1 ring region dead) ----
#pragma unroll
    for (int c = 0; c < 3; ++c) {
        const int cc = (c + rot) & 31;
        const u8* src = WTc + cc * 16384 + w * 2048 + lane * 16;
        u8* dst = pool + G2BASE + ((c & 3) << 14) + w * 2048;
#pragma unroll
        for (int i = 0; i < 2; ++i) gl_lds16(src + i * 1024, dst + i * 1024);
    }

    // ---- combine max/argmax + compact loss ----
    if (t < 32) {
        float mx = sPM[0][t]; int bid = sPI[0][t];
#pragma unroll
        for (int q = 1; q < 4; ++q) {
            float m2 = sPM[q][t]; int i2 = sPI[q][t];
            if (m2 > mx || (m2 == mx && i2 < bid)) { mx = m2; bid = i2; }
        }
        sMax[t] = mx;
        float ss = 0.f;
#pragma unroll
        for (int q = 0; q < 8; ++q) ss += sSSp[q][t];
        float term = ss - 2.f * mx + sqv[bid];
#pragma unroll
        for (int d = 1; d < 32; d <<= 1) term += __shfl_xor(term, d);
        if (t == 0) atomicAdd(loss, term * (1.0f / 8388608.0f));
    }
    lds_bar();

    // ---- exp (in-place) + Z ----
    {
        const float mxv = sMax[row_a];
        float z = 0.f;
#pragma unroll
        for (int c = 0; c < 32; ++c)
#pragma unroll
            for (int e = 0; e < 4; ++e) {
                float a_ = __expf(acc[c][e] - mxv);
                acc[c][e] = a_;
                z += a_;
            }
        z += __shfl_xor(z, 16); z += __shfl_xor(z, 32);
        if (lane < 16) sPZ[sq4][rt * 16 + lane] = z;
    }
    lds_bar();
    if (t < 32) sThr[t] = 0.0025f * (sPZ[0][t] + sPZ[1][t] + sPZ[2][t] + sPZ[3][t]);
    lds_bar();

    // ---- shrink mask + denom + packed fp8 a-write (u32 per chunk) ----
    {
        const float thrv = sThr[row_a];
        const int rowbase = row_a * SLSTR + sb;
        float den = 0.f;
#pragma unroll
        for (int c = 0; c < 32; ++c) {
            const int off = rowbase + (((c + rot) & 31) << 6);
            u32 pk = 0;
#pragma unroll
            for (int e = 0; e < 4; ++e) {
                float a_ = acc[c][e];
                if (a_ > thrv) { den += a_; pk |= f2e4m3_fast(a_ * 64.f) << (e * 8); }
            }
            *(u32*)(pool + off) = pk;
        }
        den += __shfl_xor(den, 16); den += __shfl_xor(den, 32);
        if (lane < 16) sPD[sq4][rt * 16 + lane] = den;
    }
    lds_bar();
    if (t < 32) {
        float den = sPD[0][t] + sPD[1][t] + sPD[2][t] + sPD[3][t];
        sInv[t] = den > 0.f ? 1.0f / (1024.0f * den) : 0.0f;
    }
    lds_bar();

    // ---- GEMM2: out = a_fp8 @ WT_fp8, rotated chunk order ----
    f32x4 oa00 = {0.f,0.f,0.f,0.f}, oa01 = {0.f,0.f,0.f,0.f};
    f32x4 oa10 = {0.f,0.f,0.f,0.f}, oa11 = {0.f,0.f,0.f,0.f};
    const int ch0 = (w * 2) * 16 + ar;
    const int ch1 = (w * 2 + 1) * 16 + ar;
    int bo[2][2];
#pragma unroll
    for (int kk = 0; kk < 2; ++kk) {
        bo[0][kk] = (ch0 * 64 + kk * 32 + ag * 8) ^ ((ch0 & 7) << 3);
        bo[1][kk] = (ch1 * 64 + kk * 32 + ag * 8) ^ ((ch1 & 7) << 3);
    }
    const u8* sLr0 = pool + ar * SLSTR + ag * 8;
    const u8* sLr1 = pool + (16 + ar) * SLSTR + ag * 8;
#pragma unroll
    for (int c = 0; c < 32; ++c) {
        if (c <= 29)      asm volatile("s_waitcnt vmcnt(4)" ::: "memory");
        else if (c == 30) asm volatile("s_waitcnt vmcnt(2)" ::: "memory");
        else              asm volatile("s_waitcnt vmcnt(0)" ::: "memory");
        pipe_bar();
        if (c <= 28) {
            const int cn = (c + 3 + rot) & 31;
            const u8* src = WTc + cn * 16384 + w * 2048 + lane * 16;
            u8* dst = pool + G2BASE + (((c + 3) & 3) << 14) + w * 2048;
#pragma unroll
            for (int i = 0; i < 2; ++i) gl_lds16(src + i * 1024, dst + i * 1024);
        }
        const u8* base = pool + G2BASE + ((c & 3) << 14);
        const int cc64 = ((c + rot) & 31) << 6;
        long long A00 = *(const long long*)(sLr0 + cc64);
        long long A01 = *(const long long*)(sLr0 + cc64 + 32);
        long long A10 = *(const long long*)(sLr1 + cc64);
        long long A11 = *(const long long*)(sLr1 + cc64 + 32);
        long long B00 = *(const long long*)(base + bo[0][0]);
        long long B01 = *(const long long*)(base + bo[0][1]);
        long long B10 = *(const long long*)(base + bo[1][0]);
        long long B11 = *(const long long*)(base + bo[1][1]);
        oa00 = __builtin_amdgcn_mfma_f32_16x16x32_fp8_fp8(A00, B00, oa00, 0, 0, 0);
        oa00 = __builtin_amdgcn_mfma_f32_16x16x32_fp8_fp8(A01, B01, oa00, 0, 0, 0);
        oa01 = __builtin_amdgcn_mfma_f32_16x16x32_fp8_fp8(A10, B00, oa01, 0, 0, 0);
        oa01 = __builtin_amdgcn_mfma_f32_16x16x32_fp8_fp8(A11, B01, oa01, 0, 0, 0);
        oa10 = __builtin_amdgcn_mfma_f32_16x16x32_fp8_fp8(A00, B10, oa10, 0, 0, 0);
        oa10 = __builtin_amdgcn_mfma_f32_16x16x32_fp8_fp8(A01, B11, oa10, 0, 0, 0);
        oa11 = __builtin_amdgcn_mfma_f32_16x16x32_fp8_fp8(A10, B10, oa11, 0, 0, 0);
        oa11 = __builtin_amdgcn_mfma_f32_16x16x32_fp8_fp8(A11, B11, oa11, 0, 0, 0);
    }
    lds_bar();   // all a-reads done; reuse pool as f32 out-stage

    {
        float* sO = (float*)pool;
#pragma unroll
        for (int i = 0; i < 4; ++i) {
            int r0 = ag * 4 + i, r1 = 16 + ag * 4 + i;
            sO[r0 * OSTR + ch0] = oa00[i] * sInv[r0];
            sO[r1 * OSTR + ch0] = oa01[i] * sInv[r1];
            sO[r0 * OSTR + ch1] = oa10[i] * sInv[r0];
            sO[r1 * OSTR + ch1] = oa11[i] * sInv[r1];
        }
    }
    lds_bar();
    {
        const float* sO = (const float*)pool;
        const int hw = t & 31, cq = t >> 5;
        float* op = out + (size_t)b * 262144 + hw0 + hw;
#pragma unroll
        for (int i = 0; i < 16; ++i) {
            int ch = cq + (i << 4);
            op[ch * 1024] = sO[hw * OSTR + ch];
        }
    }
}

// ---------------- distance loss (bf16 W@W^T from swizzled Wbs) ----------------
__global__ __launch_bounds__(256) void dist_kernel(const u16* __restrict__ Wbs,
                                                   const float* __restrict__ sqv,
                                                   float* __restrict__ dl) {
    __shared__ float red[4];
    int t = threadIdx.x, w = t >> 6, lane = t & 63;
    int ar = lane & 15, ag = lane >> 4;
    int i0 = blockIdx.x << 4;
    int si = i0 + ar;
    s16x8 af[8];
#pragma unroll
    for (int q = 0; q < 8; ++q)
        af[q] = *(const s16x8*)&Wbs[si * 256 + ((q * 32 + ag * 8) ^ ((si & 7) << 3))];
    float sqi[4];
#pragma unroll
    for (int e = 0; e < 4; ++e) sqi[e] = sqv[i0 + (ag << 2) + e];
    float sum = 0.f;
    for (int jt = w; jt < 125; jt += 4) {
        int j0 = jt << 4, sj0 = j0 + ar;
        f32x4 acc = {0.f, 0.f, 0.f, 0.f};
#pragma unroll
        for (int q = 0; q < 8; ++q) {
            s16x8 bf = *(const s16x8*)&Wbs[sj0 * 256 + ((q * 32 + ag * 8) ^ ((sj0 & 7) << 3))];
            acc = __builtin_amdgcn_mfma_f32_16x16x32_bf16(af[q], bf, acc, 0, 0, 0);
        }
        float sqj = sqv[sj0];
#pragma unroll
        for (int e = 0; e < 4; ++e) {
            float dist = 1.0f - (sqi[e] + sqj - 2.0f * acc[e]);
            sum += dist > 0.f ? dist : 0.f;
        }
    }
#pragma unroll
    for (int d = 1; d < 64; d <<= 1) sum += __shfl_xor(sum, d);
    if (lane == 0) red[w] = sum;
    __syncthreads();
    if (t == 0) {
        float s = red[0] + red[1] + red[2] + red[3];
        atomicAdd(dl, s * (1.0f / (2000.0f * 1999.0f)));
    }
}

extern "C" void kernel_launch(void* const* d_in, const int* in_sizes, int n_in,
                              void* d_out, int out_size, void* d_ws, size_t ws_size,
                              hipStream_t stream) {
    (void)in_sizes; (void)n_in; (void)out_size; (void)ws_size;
    const float* inp  = (const float*)d_in[0];
    const float* W    = (const float*)d_in[2];
    const float* posb = (const float*)d_in[3];
    float* out = (float*)d_out;

    u16* Wbs = (u16*)d_ws;                                   // 2048*256*2 = 1,048,576 B
    u8*  WTc = (u8*)d_ws + 1048576;                          // 32*16384   =   524,288 B
    float* sqv = (float*)((u8*)d_ws + 1048576 + 524288);     // 2000*4     =     8,000 B

    hipLaunchKernelGGL(prep_kernel, dim3(250), dim3(256), 0, stream, W, Wbs, WTc, sqv, out + OUTN);
    hipLaunchKernelGGL(main_kernel, dim3(1024), dim3(512), 0, stream, inp, posb, Wbs, WTc, sqv, out, out + OUTN);
    hipLaunchKernelGGL(dist_kernel, dim3(125), dim3(256), 0, stream, Wbs, sqv, out + OUTN + 1);
}